// Round 1
// baseline (2295.985 us; speedup 1.0000x reference)
//
#include <hip/hip_runtime.h>
#include <hip/hip_bf16.h>
#include <math.h>

#define BB 2
#define LL 2048
#define DMODEL 1024
#define DINNER 2048
#define DSTATE 16
#define DTRANK 64
#define NROWS (BB * LL)   // 4096

// ---------------- LayerNorm: one block per row (1024 floats) ----------------
__global__ __launch_bounds__(256) void ln_kernel(const float* __restrict__ x,
                                                 const float* __restrict__ w,
                                                 const float* __restrict__ b,
                                                 float* __restrict__ xn) {
    int row = blockIdx.x;
    const float* xr = x + (size_t)row * DMODEL;
    float4 v = reinterpret_cast<const float4*>(xr)[threadIdx.x];
    float s  = v.x + v.y + v.z + v.w;
    float ss = v.x * v.x + v.y * v.y + v.z * v.z + v.w * v.w;
    // wave64 reduce
    for (int off = 32; off > 0; off >>= 1) {
        s  += __shfl_down(s, off);
        ss += __shfl_down(ss, off);
    }
    __shared__ float red0[4], red1[4];
    __shared__ float mu_s, rstd_s;
    int lane = threadIdx.x & 63, wv = threadIdx.x >> 6;
    if (lane == 0) { red0[wv] = s; red1[wv] = ss; }
    __syncthreads();
    if (threadIdx.x == 0) {
        float S = red0[0] + red0[1] + red0[2] + red0[3];
        float SS = red1[0] + red1[1] + red1[2] + red1[3];
        float mu = S * (1.0f / DMODEL);
        float var = SS * (1.0f / DMODEL) - mu * mu;
        mu_s = mu;
        rstd_s = rsqrtf(var + 1e-5f);
    }
    __syncthreads();
    float mu = mu_s, rstd = rstd_s;
    float4 wv4 = reinterpret_cast<const float4*>(w)[threadIdx.x];
    float4 bv4 = reinterpret_cast<const float4*>(b)[threadIdx.x];
    float4 o;
    o.x = (v.x - mu) * rstd * wv4.x + bv4.x;
    o.y = (v.y - mu) * rstd * wv4.y + bv4.y;
    o.z = (v.z - mu) * rstd * wv4.z + bv4.z;
    o.w = (v.w - mu) * rstd * wv4.w + bv4.w;
    reinterpret_cast<float4*>(xn + (size_t)row * DMODEL)[threadIdx.x] = o;
}

// ---------------- Generic fp32 GEMM: C[M,N] = A[M,K] * W[N,K]^T --------------
// EPI: 0 = none; 1 = softplus(acc + bias[n]); 2 = acc + R[m*ldc+n]
// M is always a multiple of 64 here (4096). N may not be (x_proj N=96).
template <int EPI>
__global__ __launch_bounds__(256) void gemm_kernel(
    const float* __restrict__ A, int lda,
    const float* __restrict__ W, int ldw,
    float* __restrict__ C, int ldc,
    int N, int K,
    const float* __restrict__ bias,
    const float* __restrict__ R) {
    __shared__ float As[16][64];
    __shared__ float Ws[16][64];
    int m0 = blockIdx.y * 64;
    int n0 = blockIdx.x * 64;
    int tid = threadIdx.x;
    int tm = tid >> 4, tn = tid & 15;      // 16x16 thread grid, 4x4 each
    int lr = tid >> 2;                     // 0..63 tile row for loads
    int lk = (tid & 3) << 2;               // 0,4,8,12 k-offset for loads

    float acc[4][4] = {};

    for (int k0 = 0; k0 < K; k0 += 16) {
        float4 av = *reinterpret_cast<const float4*>(A + (size_t)(m0 + lr) * lda + k0 + lk);
        float4 wvv;
        int wn = n0 + lr;
        if (wn < N)
            wvv = *reinterpret_cast<const float4*>(W + (size_t)wn * ldw + k0 + lk);
        else
            wvv = make_float4(0.f, 0.f, 0.f, 0.f);
        __syncthreads();   // previous iteration's LDS reads done
        As[lk + 0][lr] = av.x; As[lk + 1][lr] = av.y;
        As[lk + 2][lr] = av.z; As[lk + 3][lr] = av.w;
        Ws[lk + 0][lr] = wvv.x; Ws[lk + 1][lr] = wvv.y;
        Ws[lk + 2][lr] = wvv.z; Ws[lk + 3][lr] = wvv.w;
        __syncthreads();
#pragma unroll
        for (int k = 0; k < 16; k++) {
            float4 a = *reinterpret_cast<const float4*>(&As[k][tm << 2]);
            float4 bv = *reinterpret_cast<const float4*>(&Ws[k][tn << 2]);
            float ar[4] = {a.x, a.y, a.z, a.w};
            float br[4] = {bv.x, bv.y, bv.z, bv.w};
#pragma unroll
            for (int i = 0; i < 4; i++)
#pragma unroll
                for (int j = 0; j < 4; j++)
                    acc[i][j] = fmaf(ar[i], br[j], acc[i][j]);
        }
    }
#pragma unroll
    for (int i = 0; i < 4; i++) {
        int m = m0 + (tm << 2) + i;
#pragma unroll
        for (int j = 0; j < 4; j++) {
            int n = n0 + (tn << 2) + j;
            if (n < N) {
                float v = acc[i][j];
                if (EPI == 1) {
                    v += bias[n];
                    v = (v > 20.f) ? v : log1pf(__expf(v));
                }
                if (EPI == 2) {
                    v += R[(size_t)m * ldc + n];
                }
                C[(size_t)m * ldc + n] = v;
            }
        }
    }
}

// ------------- causal depthwise conv (width 4) + SiLU ------------------------
// u[r, c] = silu(conv_b[c] + sum_k xc[r-3+k, c] * w[c, k]),  xc = xz[:, 0:2048]
__global__ __launch_bounds__(256) void conv_silu_kernel(
    const float* __restrict__ xz, const float* __restrict__ cw,
    const float* __restrict__ cb, float* __restrict__ u) {
    int c = blockIdx.x * 256 + threadIdx.x;
    int r = blockIdx.y;            // b*L + l
    int l = r & (LL - 1);
    float4 wv = reinterpret_cast<const float4*>(cw)[c];
    const float* p = xz + (size_t)r * (2 * DINNER) + c;
    float acc = cb[c];
    if (l >= 3) acc = fmaf(p[-3 * (2 * DINNER)], wv.x, acc);
    if (l >= 2) acc = fmaf(p[-2 * (2 * DINNER)], wv.y, acc);
    if (l >= 1) acc = fmaf(p[-1 * (2 * DINNER)], wv.z, acc);
    acc = fmaf(p[0], wv.w, acc);
    float sig = 1.f / (1.f + __expf(-acc));
    u[(size_t)r * DINNER + c] = acc * sig;
}

// ------------------- selective scan: one thread per (b, d) -------------------
// h[s] <- exp(dt*A[d,s]) * h[s] + dt*u*B[t,s];  y_t = sum_s h[s]*C[t,s]
// then y = (y + u*D[d]) * silu(z)
__global__ __launch_bounds__(256) void scan_kernel(
    const float* __restrict__ dt, const float* __restrict__ u,
    const float* __restrict__ xdbl, const float* __restrict__ xz,
    const float* __restrict__ A_log, const float* __restrict__ Dp,
    float* __restrict__ y) {
    int b = blockIdx.x >> 3;                               // uniform per block
    int d = ((blockIdx.x & 7) << 8) + threadIdx.x;
    float a2[DSTATE];
#pragma unroll
    for (int s = 0; s < DSTATE; s++)
        a2[s] = -__expf(A_log[d * DSTATE + s]) * 1.44269504089f;  // *log2(e)
    float Dd = Dp[d];
    float h[DSTATE];
#pragma unroll
    for (int s = 0; s < DSTATE; s++) h[s] = 0.f;

    const float* dtp = dt + (size_t)b * LL * DINNER + d;
    const float* up  = u  + (size_t)b * LL * DINNER + d;
    const float* zp  = xz + (size_t)b * LL * (2 * DINNER) + DINNER + d;
    const float* xdp = xdbl + (size_t)b * LL * 96;
    float* yp = y + (size_t)b * LL * DINNER + d;

    for (int t = 0; t < LL; t++) {
        float dtv = dtp[(size_t)t * DINNER];
        float uv  = up[(size_t)t * DINNER];
        float du  = dtv * uv;
        const float* xr = xdp + t * 96;   // uniform address -> scalar loads
        float yv = 0.f;
#pragma unroll
        for (int s = 0; s < DSTATE; s++) {
            float dA = exp2f(dtv * a2[s]);
            h[s] = fmaf(dA, h[s], du * xr[64 + s]);
            yv = fmaf(h[s], xr[80 + s], yv);
        }
        float zv = zp[(size_t)t * (2 * DINNER)];
        float sig = 1.f / (1.f + __expf(-zv));
        yv = (yv + uv * Dd) * (zv * sig);
        yp[(size_t)t * DINNER] = yv;
    }
}

// ---------------------------------------------------------------------------
extern "C" void kernel_launch(void* const* d_in, const int* in_sizes, int n_in,
                              void* d_out, int out_size, void* d_ws, size_t ws_size,
                              hipStream_t stream) {
    const float* x         = (const float*)d_in[0];
    const float* norm_w    = (const float*)d_in[1];
    const float* norm_b    = (const float*)d_in[2];
    const float* in_proj_w = (const float*)d_in[3];
    const float* conv_w    = (const float*)d_in[4];
    const float* conv_b    = (const float*)d_in[5];
    const float* x_proj_w  = (const float*)d_in[6];
    const float* dt_proj_w = (const float*)d_in[7];
    const float* dt_proj_b = (const float*)d_in[8];
    const float* A_log     = (const float*)d_in[9];
    const float* Dp        = (const float*)d_in[10];
    const float* out_proj_w= (const float*)d_in[11];
    float* out = (float*)d_out;

    float* ws   = (float*)d_ws;
    float* xn   = ws;                                  // 4096*1024  =  4.19M
    float* xz   = xn   + (size_t)NROWS * DMODEL;       // 4096*4096  = 16.78M
    float* u    = xz   + (size_t)NROWS * 2 * DINNER;   // 4096*2048  =  8.39M
    float* xdbl = u    + (size_t)NROWS * DINNER;       // 4096*96
    float* dtb  = xdbl + (size_t)NROWS * 96;           // 4096*2048
    float* yb   = dtb  + (size_t)NROWS * DINNER;       // 4096*2048
    // total ~46.5M floats = 186 MB

    // 1) LayerNorm
    ln_kernel<<<NROWS, 256, 0, stream>>>(x, norm_w, norm_b, xn);
    // 2) in_proj: xz[4096,4096] = xn[4096,1024] @ in_proj_w[4096,1024]^T
    gemm_kernel<0><<<dim3((2 * DINNER) / 64, NROWS / 64), 256, 0, stream>>>(
        xn, DMODEL, in_proj_w, DMODEL, xz, 2 * DINNER, 2 * DINNER, DMODEL, nullptr, nullptr);
    // 3) causal depthwise conv + SiLU -> u[4096,2048]
    conv_silu_kernel<<<dim3(DINNER / 256, NROWS), 256, 0, stream>>>(xz, conv_w, conv_b, u);
    // 4) x_proj: xdbl[4096,96] = u @ x_proj_w[96,2048]^T
    gemm_kernel<0><<<dim3(2, NROWS / 64), 256, 0, stream>>>(
        u, DINNER, x_proj_w, DINNER, xdbl, 96, 96, DINNER, nullptr, nullptr);
    // 5) dt_proj + softplus: dtb[4096,2048] = softplus(xdbl[:, :64] @ dt_proj_w^T + b)
    gemm_kernel<1><<<dim3(DINNER / 64, NROWS / 64), 256, 0, stream>>>(
        xdbl, 96, dt_proj_w, DTRANK, dtb, DINNER, DINNER, DTRANK, dt_proj_b, nullptr);
    // 6) selective scan + D skip + SiLU(z) gate -> yb[4096,2048]
    scan_kernel<<<(BB * DINNER) / 256, 256, 0, stream>>>(dtb, u, xdbl, xz, A_log, Dp, yb);
    // 7) out_proj + residual: out = x + yb @ out_proj_w[1024,2048]^T
    gemm_kernel<2><<<dim3(DMODEL / 64, NROWS / 64), 256, 0, stream>>>(
        yb, DINNER, out_proj_w, DINNER, out, DMODEL, DMODEL, DINNER, nullptr, x);
}

// Round 2
// 1148.351 us; speedup vs baseline: 1.9994x; 1.9994x over previous
//
#include <hip/hip_runtime.h>
#include <hip/hip_bf16.h>
#include <math.h>

#define BB 2
#define LL 2048
#define DMODEL 1024
#define DINNER 2048
#define DSTATE 16
#define DTRANK 64
#define NROWS (BB * LL)   // 4096
#define NC 32             // number of time chunks
#define CK 64             // chunk length (NC*CK == LL)

// ---------------- LayerNorm: one block per row (1024 floats) ----------------
__global__ __launch_bounds__(256) void ln_kernel(const float* __restrict__ x,
                                                 const float* __restrict__ w,
                                                 const float* __restrict__ b,
                                                 float* __restrict__ xn) {
    int row = blockIdx.x;
    const float* xr = x + (size_t)row * DMODEL;
    float4 v = reinterpret_cast<const float4*>(xr)[threadIdx.x];
    float s  = v.x + v.y + v.z + v.w;
    float ss = v.x * v.x + v.y * v.y + v.z * v.z + v.w * v.w;
    for (int off = 32; off > 0; off >>= 1) {
        s  += __shfl_down(s, off);
        ss += __shfl_down(ss, off);
    }
    __shared__ float red0[4], red1[4];
    __shared__ float mu_s, rstd_s;
    int lane = threadIdx.x & 63, wv = threadIdx.x >> 6;
    if (lane == 0) { red0[wv] = s; red1[wv] = ss; }
    __syncthreads();
    if (threadIdx.x == 0) {
        float S = red0[0] + red0[1] + red0[2] + red0[3];
        float SS = red1[0] + red1[1] + red1[2] + red1[3];
        float mu = S * (1.0f / DMODEL);
        float var = SS * (1.0f / DMODEL) - mu * mu;
        mu_s = mu;
        rstd_s = rsqrtf(var + 1e-5f);
    }
    __syncthreads();
    float mu = mu_s, rstd = rstd_s;
    float4 wv4 = reinterpret_cast<const float4*>(w)[threadIdx.x];
    float4 bv4 = reinterpret_cast<const float4*>(b)[threadIdx.x];
    float4 o;
    o.x = (v.x - mu) * rstd * wv4.x + bv4.x;
    o.y = (v.y - mu) * rstd * wv4.y + bv4.y;
    o.z = (v.z - mu) * rstd * wv4.z + bv4.z;
    o.w = (v.w - mu) * rstd * wv4.w + bv4.w;
    reinterpret_cast<float4*>(xn + (size_t)row * DMODEL)[threadIdx.x] = o;
}

// ---------------- Generic fp32 GEMM: C[M,N] = A[M,K] * W[N,K]^T --------------
template <int EPI>
__global__ __launch_bounds__(256) void gemm_kernel(
    const float* __restrict__ A, int lda,
    const float* __restrict__ W, int ldw,
    float* __restrict__ C, int ldc,
    int N, int K,
    const float* __restrict__ bias,
    const float* __restrict__ R) {
    __shared__ float As[16][64];
    __shared__ float Ws[16][64];
    int m0 = blockIdx.y * 64;
    int n0 = blockIdx.x * 64;
    int tid = threadIdx.x;
    int tm = tid >> 4, tn = tid & 15;
    int lr = tid >> 2;
    int lk = (tid & 3) << 2;

    float acc[4][4] = {};

    for (int k0 = 0; k0 < K; k0 += 16) {
        float4 av = *reinterpret_cast<const float4*>(A + (size_t)(m0 + lr) * lda + k0 + lk);
        float4 wvv;
        int wn = n0 + lr;
        if (wn < N)
            wvv = *reinterpret_cast<const float4*>(W + (size_t)wn * ldw + k0 + lk);
        else
            wvv = make_float4(0.f, 0.f, 0.f, 0.f);
        __syncthreads();
        As[lk + 0][lr] = av.x; As[lk + 1][lr] = av.y;
        As[lk + 2][lr] = av.z; As[lk + 3][lr] = av.w;
        Ws[lk + 0][lr] = wvv.x; Ws[lk + 1][lr] = wvv.y;
        Ws[lk + 2][lr] = wvv.z; Ws[lk + 3][lr] = wvv.w;
        __syncthreads();
#pragma unroll
        for (int k = 0; k < 16; k++) {
            float4 a = *reinterpret_cast<const float4*>(&As[k][tm << 2]);
            float4 bv = *reinterpret_cast<const float4*>(&Ws[k][tn << 2]);
            float ar[4] = {a.x, a.y, a.z, a.w};
            float br[4] = {bv.x, bv.y, bv.z, bv.w};
#pragma unroll
            for (int i = 0; i < 4; i++)
#pragma unroll
                for (int j = 0; j < 4; j++)
                    acc[i][j] = fmaf(ar[i], br[j], acc[i][j]);
        }
    }
#pragma unroll
    for (int i = 0; i < 4; i++) {
        int m = m0 + (tm << 2) + i;
#pragma unroll
        for (int j = 0; j < 4; j++) {
            int n = n0 + (tn << 2) + j;
            if (n < N) {
                float v = acc[i][j];
                if (EPI == 1) {
                    v += bias[n];
                    v = (v > 20.f) ? v : log1pf(__expf(v));
                }
                if (EPI == 2) {
                    v += R[(size_t)m * ldc + n];
                }
                C[(size_t)m * ldc + n] = v;
            }
        }
    }
}

// ------------- causal depthwise conv (width 4) + SiLU ------------------------
__global__ __launch_bounds__(256) void conv_silu_kernel(
    const float* __restrict__ xz, const float* __restrict__ cw,
    const float* __restrict__ cb, float* __restrict__ u) {
    int c = blockIdx.x * 256 + threadIdx.x;
    int r = blockIdx.y;
    int l = r & (LL - 1);
    float4 wv = reinterpret_cast<const float4*>(cw)[c];
    const float* p = xz + (size_t)r * (2 * DINNER) + c;
    float acc = cb[c];
    if (l >= 3) acc = fmaf(p[-3 * (2 * DINNER)], wv.x, acc);
    if (l >= 2) acc = fmaf(p[-2 * (2 * DINNER)], wv.y, acc);
    if (l >= 1) acc = fmaf(p[-1 * (2 * DINNER)], wv.z, acc);
    acc = fmaf(p[0], wv.w, acc);
    float sig = 1.f / (1.f + __expf(-acc));
    u[(size_t)r * DINNER + c] = acc * sig;
}

// ------------------- chunked selective scan ---------------------------------
// Recurrence per (b,d,s): h <- dA*h + dt*u*B[t,s].  Split L into NC chunks of CK.
// Pass 1: per (b,chunk,d): local scan from h=0 -> hloc, and decay product aprod.
// Layout of hloc/aprod: [(b*NC + c)*DSTATE + s][DINNER] + d  (d fastest: coalesced)
__global__ __launch_bounds__(256) void scan_pass1(
    const float* __restrict__ dt, const float* __restrict__ u,
    const float* __restrict__ xdbl, const float* __restrict__ A_log,
    float* __restrict__ hloc, float* __restrict__ aprod) {
    int bc = blockIdx.x >> 3;              // b*NC + c   (uniform per block)
    int b = bc >> 5, c = bc & (NC - 1);
    int d = ((blockIdx.x & 7) << 8) + threadIdx.x;
    float a2[DSTATE];
#pragma unroll
    for (int s = 0; s < DSTATE; s++)
        a2[s] = -__expf(A_log[d * DSTATE + s]) * 1.44269504089f;
    float h[DSTATE], ap[DSTATE];
#pragma unroll
    for (int s = 0; s < DSTATE; s++) { h[s] = 0.f; ap[s] = 1.f; }

    int t0 = c * CK;
    const float* dtp = dt + ((size_t)b * LL + t0) * DINNER + d;
    const float* up  = u  + ((size_t)b * LL + t0) * DINNER + d;
    const float* xr0 = xdbl + ((size_t)b * LL + t0) * 96;

    for (int t = 0; t < CK; t++) {
        float dtv = dtp[(size_t)t * DINNER];
        float uv  = up[(size_t)t * DINNER];
        float du  = dtv * uv;
        const float* xr = xr0 + t * 96;    // uniform -> scalar loads
#pragma unroll
        for (int s = 0; s < DSTATE; s++) {
            float dA = exp2f(dtv * a2[s]);
            h[s] = fmaf(dA, h[s], du * xr[64 + s]);
            ap[s] *= dA;
        }
    }
    size_t base = ((size_t)bc * DSTATE) * DINNER + d;
#pragma unroll
    for (int s = 0; s < DSTATE; s++) {
        hloc[base + (size_t)s * DINNER]  = h[s];
        aprod[base + (size_t)s * DINNER] = ap[s];
    }
}

// Pass 2: exclusive scan over chunks per (b,d,s).  hloc is overwritten with the
// chunk-INITIAL state.  65536 threads, d fastest for coalescing.
__global__ __launch_bounds__(256) void scan_pass2(
    float* __restrict__ hloc, const float* __restrict__ aprod) {
    int idx = blockIdx.x * 256 + threadIdx.x;       // (b*DSTATE + s)*DINNER + d
    int d = idx & (DINNER - 1);
    int s = (idx >> 11) & (DSTATE - 1);
    int b = idx >> 15;
    float run = 0.f;
    for (int c = 0; c < NC; c++) {
        size_t off = ((size_t)((b * NC + c) * DSTATE + s)) * DINNER + d;
        float hl = hloc[off];
        float ap = aprod[off];
        hloc[off] = run;                 // exclusive prefix: initial state
        run = fmaf(ap, run, hl);
    }
}

// Pass 3: redo each chunk from its true initial state; emit gated output.
__global__ __launch_bounds__(256) void scan_pass3(
    const float* __restrict__ dt, const float* __restrict__ u,
    const float* __restrict__ xdbl, const float* __restrict__ xz,
    const float* __restrict__ A_log, const float* __restrict__ Dp,
    const float* __restrict__ hinit, float* __restrict__ y) {
    int bc = blockIdx.x >> 3;
    int b = bc >> 5, c = bc & (NC - 1);
    int d = ((blockIdx.x & 7) << 8) + threadIdx.x;
    float a2[DSTATE];
#pragma unroll
    for (int s = 0; s < DSTATE; s++)
        a2[s] = -__expf(A_log[d * DSTATE + s]) * 1.44269504089f;
    float Dd = Dp[d];
    float h[DSTATE];
    size_t base = ((size_t)bc * DSTATE) * DINNER + d;
#pragma unroll
    for (int s = 0; s < DSTATE; s++) h[s] = hinit[base + (size_t)s * DINNER];

    int t0 = c * CK;
    const float* dtp = dt + ((size_t)b * LL + t0) * DINNER + d;
    const float* up  = u  + ((size_t)b * LL + t0) * DINNER + d;
    const float* zp  = xz + ((size_t)b * LL + t0) * (2 * DINNER) + DINNER + d;
    const float* xr0 = xdbl + ((size_t)b * LL + t0) * 96;
    float* yp = y + ((size_t)b * LL + t0) * DINNER + d;

    for (int t = 0; t < CK; t++) {
        float dtv = dtp[(size_t)t * DINNER];
        float uv  = up[(size_t)t * DINNER];
        float du  = dtv * uv;
        const float* xr = xr0 + t * 96;
        float yv = 0.f;
#pragma unroll
        for (int s = 0; s < DSTATE; s++) {
            float dA = exp2f(dtv * a2[s]);
            h[s] = fmaf(dA, h[s], du * xr[64 + s]);
            yv = fmaf(h[s], xr[80 + s], yv);
        }
        float zv = zp[(size_t)t * (2 * DINNER)];
        float sig = 1.f / (1.f + __expf(-zv));
        yv = (yv + uv * Dd) * (zv * sig);
        yp[(size_t)t * DINNER] = yv;
    }
}

// ---------------------------------------------------------------------------
extern "C" void kernel_launch(void* const* d_in, const int* in_sizes, int n_in,
                              void* d_out, int out_size, void* d_ws, size_t ws_size,
                              hipStream_t stream) {
    const float* x         = (const float*)d_in[0];
    const float* norm_w    = (const float*)d_in[1];
    const float* norm_b    = (const float*)d_in[2];
    const float* in_proj_w = (const float*)d_in[3];
    const float* conv_w    = (const float*)d_in[4];
    const float* conv_b    = (const float*)d_in[5];
    const float* x_proj_w  = (const float*)d_in[6];
    const float* dt_proj_w = (const float*)d_in[7];
    const float* dt_proj_b = (const float*)d_in[8];
    const float* A_log     = (const float*)d_in[9];
    const float* Dp        = (const float*)d_in[10];
    const float* out_proj_w= (const float*)d_in[11];
    float* out = (float*)d_out;

    float* ws   = (float*)d_ws;
    float* xn   = ws;                                  // 4096*1024 = 4.19M (dead after in_proj)
    float* xz   = xn   + (size_t)NROWS * DMODEL;       // 4096*4096
    float* u    = xz   + (size_t)NROWS * 2 * DINNER;   // 4096*2048
    float* xdbl = u    + (size_t)NROWS * DINNER;       // 4096*96
    float* dtb  = xdbl + (size_t)NROWS * 96;           // 4096*2048
    float* yb   = dtb  + (size_t)NROWS * DINNER;       // 4096*2048
    // scan scratch aliases xn (dead after kernel 2): 2 x 2.097M floats = 4.19M
    float* hloc  = xn;                                 // B*NC*DSTATE*DINNER
    float* aprod = xn + (size_t)BB * NC * DSTATE * DINNER;

    // 1) LayerNorm
    ln_kernel<<<NROWS, 256, 0, stream>>>(x, norm_w, norm_b, xn);
    // 2) in_proj
    gemm_kernel<0><<<dim3((2 * DINNER) / 64, NROWS / 64), 256, 0, stream>>>(
        xn, DMODEL, in_proj_w, DMODEL, xz, 2 * DINNER, 2 * DINNER, DMODEL, nullptr, nullptr);
    // 3) conv + SiLU
    conv_silu_kernel<<<dim3(DINNER / 256, NROWS), 256, 0, stream>>>(xz, conv_w, conv_b, u);
    // 4) x_proj
    gemm_kernel<0><<<dim3(2, NROWS / 64), 256, 0, stream>>>(
        u, DINNER, x_proj_w, DINNER, xdbl, 96, 96, DINNER, nullptr, nullptr);
    // 5) dt_proj + softplus
    gemm_kernel<1><<<dim3(DINNER / 64, NROWS / 64), 256, 0, stream>>>(
        xdbl, 96, dt_proj_w, DTRANK, dtb, DINNER, DINNER, DTRANK, dt_proj_b, nullptr);
    // 6) chunked selective scan (3 passes) -> yb
    scan_pass1<<<BB * NC * (DINNER / 256), 256, 0, stream>>>(dtb, u, xdbl, A_log, hloc, aprod);
    scan_pass2<<<(BB * DSTATE * DINNER) / 256, 256, 0, stream>>>(hloc, aprod);
    scan_pass3<<<BB * NC * (DINNER / 256), 256, 0, stream>>>(dtb, u, xdbl, xz, A_log, Dp, hloc, yb);
    // 7) out_proj + residual
    gemm_kernel<2><<<dim3(DMODEL / 64, NROWS / 64), 256, 0, stream>>>(
        yb, DINNER, out_proj_w, DINNER, out, DMODEL, DMODEL, DINNER, nullptr, x);
}

// Round 3
// 487.587 us; speedup vs baseline: 4.7089x; 2.3552x over previous
//
#include <hip/hip_runtime.h>
#include <hip/hip_bf16.h>
#include <math.h>

#define BB 2
#define LL 2048
#define DMODEL 1024
#define DINNER 2048
#define DSTATE 16
#define DTRANK 64
#define NROWS (BB * LL)   // 4096
#define NC 32             // number of time chunks
#define CK 64             // chunk length (NC*CK == LL)

typedef __bf16 bf16x8 __attribute__((ext_vector_type(8)));
typedef float  f32x4  __attribute__((ext_vector_type(4)));
typedef __attribute__((address_space(3))) void       as3_void;
typedef const __attribute__((address_space(1))) void as1_cvoid;

__device__ __forceinline__ ushort f2bf(float x) {
    __hip_bfloat16 h = __float2bfloat16(x);
    return *(ushort*)&h;
}

// ---------------- LayerNorm -> bf16 output ----------------------------------
__global__ __launch_bounds__(256) void ln_kernel(const float* __restrict__ x,
                                                 const float* __restrict__ w,
                                                 const float* __restrict__ b,
                                                 __hip_bfloat16* __restrict__ xn) {
    int row = blockIdx.x;
    const float* xr = x + (size_t)row * DMODEL;
    float4 v = reinterpret_cast<const float4*>(xr)[threadIdx.x];
    float s  = v.x + v.y + v.z + v.w;
    float ss = v.x * v.x + v.y * v.y + v.z * v.z + v.w * v.w;
    for (int off = 32; off > 0; off >>= 1) {
        s  += __shfl_down(s, off);
        ss += __shfl_down(ss, off);
    }
    __shared__ float red0[4], red1[4];
    __shared__ float mu_s, rstd_s;
    int lane = threadIdx.x & 63, wv = threadIdx.x >> 6;
    if (lane == 0) { red0[wv] = s; red1[wv] = ss; }
    __syncthreads();
    if (threadIdx.x == 0) {
        float S = red0[0] + red0[1] + red0[2] + red0[3];
        float SS = red1[0] + red1[1] + red1[2] + red1[3];
        float mu = S * (1.0f / DMODEL);
        float var = SS * (1.0f / DMODEL) - mu * mu;
        mu_s = mu;
        rstd_s = rsqrtf(var + 1e-5f);
    }
    __syncthreads();
    float mu = mu_s, rstd = rstd_s;
    float4 wv4 = reinterpret_cast<const float4*>(w)[threadIdx.x];
    float4 bv4 = reinterpret_cast<const float4*>(b)[threadIdx.x];
    ushort4 o;
    o.x = f2bf((v.x - mu) * rstd * wv4.x + bv4.x);
    o.y = f2bf((v.y - mu) * rstd * wv4.y + bv4.y);
    o.z = f2bf((v.z - mu) * rstd * wv4.z + bv4.z);
    o.w = f2bf((v.w - mu) * rstd * wv4.w + bv4.w);
    *reinterpret_cast<ushort4*>((ushort*)xn + (size_t)row * DMODEL + threadIdx.x * 4) = o;
}

// ---------------- f32 -> bf16 convert (weights) ------------------------------
__global__ __launch_bounds__(256) void cvt_kernel(const float* __restrict__ in,
                                                  __hip_bfloat16* __restrict__ o) {
    int i = (blockIdx.x * 256 + threadIdx.x) * 4;
    float4 v = *reinterpret_cast<const float4*>(in + i);
    ushort4 p;
    p.x = f2bf(v.x); p.y = f2bf(v.y); p.z = f2bf(v.z); p.w = f2bf(v.w);
    *reinterpret_cast<ushort4*>((ushort*)o + i) = p;
}

// ---------------- bf16 MFMA GEMM: C[M,N] = A[M,K] @ W[N,K]^T  ----------------
// 128x128 tile, BK=32, 4 waves (2x2), each wave 64x64 via 4x4 16x16x32 frags.
// EPI 0: split store (n < nsplit -> C, else C2, both ldc row stride, fp32)
// EPI 2: C[m*ldc+n] = acc + R[m*ldc+n]
template <int EPI>
__global__ __launch_bounds__(256) void gemm_bf16(
    const __hip_bfloat16* __restrict__ A, int lda,
    const __hip_bfloat16* __restrict__ W, int ldw,
    float* __restrict__ C, float* __restrict__ C2, int nsplit, int ldc,
    int K, const float* __restrict__ R) {
    __shared__ ushort As[128][32];
    __shared__ ushort Bs[128][32];
    int tid = threadIdx.x;
    int w = tid >> 6, lane = tid & 63;
    int m0 = blockIdx.y * 128, n0 = blockIdx.x * 128;
    int wr = w >> 1, wc = w & 1;

    // staging: each wave writes 64 contiguous 16B granules; row = g>>2, kgr = g&3
    int srow = (w << 4) + (lane >> 2);       // rows 0..63 (load0), +64 (load1)
    int skoff = (lane & 3) << 3;             // k element offset 0,8,16,24
    const ushort* gA = (const ushort*)A + (size_t)(m0 + srow) * lda + skoff;
    const ushort* gB = (const ushort*)W + (size_t)(n0 + srow) * ldw + skoff;
    char* ldsA0 = (char*)&As[0][0] + w * 1024;
    char* ldsB0 = (char*)&Bs[0][0] + w * 1024;

    f32x4 acc[4][4] = {};
    int frow = (lane & 15);
    int fk   = (lane >> 4) << 3;             // 0,8,16,24

    for (int k0 = 0; k0 < K; k0 += 32) {
        __syncthreads();   // previous iteration's LDS reads complete
        __builtin_amdgcn_global_load_lds((as1_cvoid*)(gA + k0),                 (as3_void*)(ldsA0),        16, 0, 0);
        __builtin_amdgcn_global_load_lds((as1_cvoid*)(gA + (size_t)64 * lda + k0), (as3_void*)(ldsA0 + 4096), 16, 0, 0);
        __builtin_amdgcn_global_load_lds((as1_cvoid*)(gB + k0),                 (as3_void*)(ldsB0),        16, 0, 0);
        __builtin_amdgcn_global_load_lds((as1_cvoid*)(gB + (size_t)64 * ldw + k0), (as3_void*)(ldsB0 + 4096), 16, 0, 0);
        __syncthreads();   // drains vmcnt(0): staged data visible

        bf16x8 af[4], bfr[4];
#pragma unroll
        for (int mi = 0; mi < 4; mi++)
            af[mi] = *(const bf16x8*)&As[wr * 64 + mi * 16 + frow][fk];
#pragma unroll
        for (int ni = 0; ni < 4; ni++)
            bfr[ni] = *(const bf16x8*)&Bs[wc * 64 + ni * 16 + frow][fk];
#pragma unroll
        for (int mi = 0; mi < 4; mi++)
#pragma unroll
            for (int ni = 0; ni < 4; ni++)
                acc[mi][ni] = __builtin_amdgcn_mfma_f32_16x16x32_bf16(
                    af[mi], bfr[ni], acc[mi][ni], 0, 0, 0);
    }

    // epilogue: row = (lane>>4)*4 + r, col = lane&15 (within 16x16 fragment)
    int crow = (lane >> 4) << 2;
    int ccol = lane & 15;
    float* Cb = C;
    int nbase = n0;
    if (EPI == 0 && n0 >= nsplit) { Cb = C2; nbase = n0 - nsplit; }
#pragma unroll
    for (int mi = 0; mi < 4; mi++) {
#pragma unroll
        for (int ni = 0; ni < 4; ni++) {
#pragma unroll
            for (int r = 0; r < 4; r++) {
                int m = m0 + wr * 64 + mi * 16 + crow + r;
                int n = nbase + wc * 64 + ni * 16 + ccol;
                float v = acc[mi][ni][r];
                if (EPI == 2) v += R[(size_t)m * ldc + n];
                Cb[(size_t)m * ldc + n] = v;
            }
        }
    }
}

// ---------------- fp32 GEMM (small: x_proj, dt_proj) -------------------------
template <int EPI>
__global__ __launch_bounds__(256) void gemm_kernel(
    const float* __restrict__ A, int lda,
    const float* __restrict__ W, int ldw,
    float* __restrict__ C, int ldc,
    int N, int K,
    const float* __restrict__ bias) {
    __shared__ float As[16][64];
    __shared__ float Ws[16][64];
    int m0 = blockIdx.y * 64;
    int n0 = blockIdx.x * 64;
    int tid = threadIdx.x;
    int tm = tid >> 4, tn = tid & 15;
    int lr = tid >> 2;
    int lk = (tid & 3) << 2;

    float acc[4][4] = {};

    for (int k0 = 0; k0 < K; k0 += 16) {
        float4 av = *reinterpret_cast<const float4*>(A + (size_t)(m0 + lr) * lda + k0 + lk);
        float4 wvv;
        int wn = n0 + lr;
        if (wn < N)
            wvv = *reinterpret_cast<const float4*>(W + (size_t)wn * ldw + k0 + lk);
        else
            wvv = make_float4(0.f, 0.f, 0.f, 0.f);
        __syncthreads();
        As[lk + 0][lr] = av.x; As[lk + 1][lr] = av.y;
        As[lk + 2][lr] = av.z; As[lk + 3][lr] = av.w;
        Ws[lk + 0][lr] = wvv.x; Ws[lk + 1][lr] = wvv.y;
        Ws[lk + 2][lr] = wvv.z; Ws[lk + 3][lr] = wvv.w;
        __syncthreads();
#pragma unroll
        for (int k = 0; k < 16; k++) {
            float4 a = *reinterpret_cast<const float4*>(&As[k][tm << 2]);
            float4 bv = *reinterpret_cast<const float4*>(&Ws[k][tn << 2]);
            float ar[4] = {a.x, a.y, a.z, a.w};
            float br[4] = {bv.x, bv.y, bv.z, bv.w};
#pragma unroll
            for (int i = 0; i < 4; i++)
#pragma unroll
                for (int j = 0; j < 4; j++)
                    acc[i][j] = fmaf(ar[i], br[j], acc[i][j]);
        }
    }
#pragma unroll
    for (int i = 0; i < 4; i++) {
        int m = m0 + (tm << 2) + i;
#pragma unroll
        for (int j = 0; j < 4; j++) {
            int n = n0 + (tn << 2) + j;
            if (n < N) {
                float v = acc[i][j];
                if (EPI == 1) {
                    v += bias[n];
                    v = (v > 20.f) ? v : log1pf(__expf(v));
                }
                C[(size_t)m * ldc + n] = v;
            }
        }
    }
}

// ------------- causal depthwise conv (width 4) + SiLU ------------------------
__global__ __launch_bounds__(256) void conv_silu_kernel(
    const float* __restrict__ xc, const float* __restrict__ cw,
    const float* __restrict__ cb, float* __restrict__ u) {
    int c = blockIdx.x * 256 + threadIdx.x;
    int r = blockIdx.y;
    int l = r & (LL - 1);
    float4 wv = reinterpret_cast<const float4*>(cw)[c];
    const float* p = xc + (size_t)r * DINNER + c;
    float acc = cb[c];
    if (l >= 3) acc = fmaf(p[-3 * DINNER], wv.x, acc);
    if (l >= 2) acc = fmaf(p[-2 * DINNER], wv.y, acc);
    if (l >= 1) acc = fmaf(p[-1 * DINNER], wv.z, acc);
    acc = fmaf(p[0], wv.w, acc);
    float sig = 1.f / (1.f + __expf(-acc));
    u[(size_t)r * DINNER + c] = acc * sig;
}

// ------------------- chunked selective scan ---------------------------------
__global__ __launch_bounds__(256) void scan_pass1(
    const float* __restrict__ dt, const float* __restrict__ u,
    const float* __restrict__ xdbl, const float* __restrict__ A_log,
    float* __restrict__ hloc, float* __restrict__ aprod) {
    int bc = blockIdx.x >> 3;
    int b = bc >> 5, c = bc & (NC - 1);
    int d = ((blockIdx.x & 7) << 8) + threadIdx.x;
    float a2[DSTATE];
#pragma unroll
    for (int s = 0; s < DSTATE; s++)
        a2[s] = -__expf(A_log[d * DSTATE + s]) * 1.44269504089f;
    float h[DSTATE], ap[DSTATE];
#pragma unroll
    for (int s = 0; s < DSTATE; s++) { h[s] = 0.f; ap[s] = 1.f; }

    int t0 = c * CK;
    const float* dtp = dt + ((size_t)b * LL + t0) * DINNER + d;
    const float* up  = u  + ((size_t)b * LL + t0) * DINNER + d;
    const float* xr0 = xdbl + ((size_t)b * LL + t0) * 96;

    for (int t = 0; t < CK; t++) {
        float dtv = dtp[(size_t)t * DINNER];
        float uv  = up[(size_t)t * DINNER];
        float du  = dtv * uv;
        const float* xr = xr0 + t * 96;
#pragma unroll
        for (int s = 0; s < DSTATE; s++) {
            float dA = exp2f(dtv * a2[s]);
            h[s] = fmaf(dA, h[s], du * xr[64 + s]);
            ap[s] *= dA;
        }
    }
    size_t base = ((size_t)bc * DSTATE) * DINNER + d;
#pragma unroll
    for (int s = 0; s < DSTATE; s++) {
        hloc[base + (size_t)s * DINNER]  = h[s];
        aprod[base + (size_t)s * DINNER] = ap[s];
    }
}

__global__ __launch_bounds__(256) void scan_pass2(
    float* __restrict__ hloc, const float* __restrict__ aprod) {
    int idx = blockIdx.x * 256 + threadIdx.x;
    int d = idx & (DINNER - 1);
    int s = (idx >> 11) & (DSTATE - 1);
    int b = idx >> 15;
    float run = 0.f;
    for (int c = 0; c < NC; c++) {
        size_t off = ((size_t)((b * NC + c) * DSTATE + s)) * DINNER + d;
        float hl = hloc[off];
        float ap = aprod[off];
        hloc[off] = run;
        run = fmaf(ap, run, hl);
    }
}

__global__ __launch_bounds__(256) void scan_pass3(
    const float* __restrict__ dt, const float* __restrict__ u,
    const float* __restrict__ xdbl, const float* __restrict__ zb,
    const float* __restrict__ A_log, const float* __restrict__ Dp,
    const float* __restrict__ hinit, __hip_bfloat16* __restrict__ y) {
    int bc = blockIdx.x >> 3;
    int b = bc >> 5, c = bc & (NC - 1);
    int d = ((blockIdx.x & 7) << 8) + threadIdx.x;
    float a2[DSTATE];
#pragma unroll
    for (int s = 0; s < DSTATE; s++)
        a2[s] = -__expf(A_log[d * DSTATE + s]) * 1.44269504089f;
    float Dd = Dp[d];
    float h[DSTATE];
    size_t base = ((size_t)bc * DSTATE) * DINNER + d;
#pragma unroll
    for (int s = 0; s < DSTATE; s++) h[s] = hinit[base + (size_t)s * DINNER];

    int t0 = c * CK;
    const float* dtp = dt + ((size_t)b * LL + t0) * DINNER + d;
    const float* up  = u  + ((size_t)b * LL + t0) * DINNER + d;
    const float* zp  = zb + ((size_t)b * LL + t0) * DINNER + d;
    const float* xr0 = xdbl + ((size_t)b * LL + t0) * 96;
    ushort* yp = (ushort*)y + ((size_t)b * LL + t0) * DINNER + d;

    for (int t = 0; t < CK; t++) {
        float dtv = dtp[(size_t)t * DINNER];
        float uv  = up[(size_t)t * DINNER];
        float du  = dtv * uv;
        const float* xr = xr0 + t * 96;
        float yv = 0.f;
#pragma unroll
        for (int s = 0; s < DSTATE; s++) {
            float dA = exp2f(dtv * a2[s]);
            h[s] = fmaf(dA, h[s], du * xr[64 + s]);
            yv = fmaf(h[s], xr[80 + s], yv);
        }
        float zv = zp[(size_t)t * DINNER];
        float sig = 1.f / (1.f + __expf(-zv));
        yv = (yv + uv * Dd) * (zv * sig);
        yp[(size_t)t * DINNER] = f2bf(yv);
    }
}

// ---------------------------------------------------------------------------
extern "C" void kernel_launch(void* const* d_in, const int* in_sizes, int n_in,
                              void* d_out, int out_size, void* d_ws, size_t ws_size,
                              hipStream_t stream) {
    const float* x         = (const float*)d_in[0];
    const float* norm_w    = (const float*)d_in[1];
    const float* norm_b    = (const float*)d_in[2];
    const float* in_proj_w = (const float*)d_in[3];
    const float* conv_w    = (const float*)d_in[4];
    const float* conv_b    = (const float*)d_in[5];
    const float* x_proj_w  = (const float*)d_in[6];
    const float* dt_proj_w = (const float*)d_in[7];
    const float* dt_proj_b = (const float*)d_in[8];
    const float* A_log     = (const float*)d_in[9];
    const float* Dp        = (const float*)d_in[10];
    const float* out_proj_w= (const float*)d_in[11];
    float* out = (float*)d_out;

    float* ws   = (float*)d_ws;
    const size_t NI = (size_t)NROWS * DINNER;          // 8,388,608
    float* xc   = ws;                                  // [4096][2048] x-branch
    float* zb   = xc + NI;                             // [4096][2048] gate z
    float* u    = zb + NI;
    float* dtb  = u + NI;
    float* xdbl = dtb + NI;                            // [4096][96]
    __hip_bfloat16* xnb = (__hip_bfloat16*)(xdbl + (size_t)NROWS * 96);
    __hip_bfloat16* ybb = xnb + (size_t)NROWS * DMODEL;
    __hip_bfloat16* wib = ybb + NI;                    // in_proj_w bf16 [4096][1024]
    __hip_bfloat16* wob = wib + (size_t)2 * DINNER * DMODEL;  // out_proj_w bf16 [1024][2048]
    // scan scratch aliases xc (dead after conv)
    float* hloc  = xc;
    float* aprod = xc + (size_t)BB * NC * DSTATE * DINNER;

    // 1) LayerNorm -> bf16
    ln_kernel<<<NROWS, 256, 0, stream>>>(x, norm_w, norm_b, xnb);
    // 1b) weight converts
    cvt_kernel<<<(2 * DINNER * DMODEL) / 1024, 256, 0, stream>>>(in_proj_w, wib);
    cvt_kernel<<<(DMODEL * DINNER) / 1024, 256, 0, stream>>>(out_proj_w, wob);
    // 2) in_proj (bf16 MFMA): writes xc (n<2048) and zb (n>=2048)
    gemm_bf16<0><<<dim3((2 * DINNER) / 128, NROWS / 128), 256, 0, stream>>>(
        xnb, DMODEL, wib, DMODEL, xc, zb, DINNER, DINNER, DMODEL, nullptr);
    // 3) conv + SiLU -> u
    conv_silu_kernel<<<dim3(DINNER / 256, NROWS), 256, 0, stream>>>(xc, conv_w, conv_b, u);
    // 4) x_proj (fp32)
    gemm_kernel<0><<<dim3(2, NROWS / 64), 256, 0, stream>>>(
        u, DINNER, x_proj_w, DINNER, xdbl, 96, 96, DINNER, nullptr);
    // 5) dt_proj + softplus (fp32)
    gemm_kernel<1><<<dim3(DINNER / 64, NROWS / 64), 256, 0, stream>>>(
        xdbl, 96, dt_proj_w, DTRANK, dtb, DINNER, DINNER, DTRANK, dt_proj_b);
    // 6) chunked selective scan -> ybb (bf16)
    scan_pass1<<<BB * NC * (DINNER / 256), 256, 0, stream>>>(dtb, u, xdbl, A_log, hloc, aprod);
    scan_pass2<<<(BB * DSTATE * DINNER) / 256, 256, 0, stream>>>(hloc, aprod);
    scan_pass3<<<BB * NC * (DINNER / 256), 256, 0, stream>>>(dtb, u, xdbl, zb, A_log, Dp, hloc, ybb);
    // 7) out_proj + residual (bf16 MFMA)
    gemm_bf16<2><<<dim3(DMODEL / 128, NROWS / 128), 256, 0, stream>>>(
        ybb, DINNER, wob, DINNER, out, nullptr, 1 << 30, DMODEL, DINNER, x);
}

// Round 4
// 430.419 us; speedup vs baseline: 5.3343x; 1.1328x over previous
//
#include <hip/hip_runtime.h>
#include <hip/hip_bf16.h>
#include <math.h>

#define BB 2
#define LL 2048
#define DMODEL 1024
#define DINNER 2048
#define DSTATE 16
#define DTRANK 64
#define NROWS (BB * LL)   // 4096
#define NC 32             // number of time chunks
#define CK 64             // chunk length (NC*CK == LL)
#define KS 16             // split-K factor for x_proj
#define KCH (DINNER / KS) // 128

typedef __bf16 bf16x8 __attribute__((ext_vector_type(8)));
typedef float  f32x4  __attribute__((ext_vector_type(4)));
typedef __attribute__((address_space(3))) void       as3_void;
typedef const __attribute__((address_space(1))) void as1_cvoid;

__device__ __forceinline__ ushort f2bf(float x) {
    __hip_bfloat16 h = __float2bfloat16(x);
    return *(ushort*)&h;
}

// ---------------- LayerNorm -> bf16 output ----------------------------------
__global__ __launch_bounds__(256) void ln_kernel(const float* __restrict__ x,
                                                 const float* __restrict__ w,
                                                 const float* __restrict__ b,
                                                 __hip_bfloat16* __restrict__ xn) {
    int row = blockIdx.x;
    const float* xr = x + (size_t)row * DMODEL;
    float4 v = reinterpret_cast<const float4*>(xr)[threadIdx.x];
    float s  = v.x + v.y + v.z + v.w;
    float ss = v.x * v.x + v.y * v.y + v.z * v.z + v.w * v.w;
    for (int off = 32; off > 0; off >>= 1) {
        s  += __shfl_down(s, off);
        ss += __shfl_down(ss, off);
    }
    __shared__ float red0[4], red1[4];
    __shared__ float mu_s, rstd_s;
    int lane = threadIdx.x & 63, wv = threadIdx.x >> 6;
    if (lane == 0) { red0[wv] = s; red1[wv] = ss; }
    __syncthreads();
    if (threadIdx.x == 0) {
        float S = red0[0] + red0[1] + red0[2] + red0[3];
        float SS = red1[0] + red1[1] + red1[2] + red1[3];
        float mu = S * (1.0f / DMODEL);
        float var = SS * (1.0f / DMODEL) - mu * mu;
        mu_s = mu;
        rstd_s = rsqrtf(var + 1e-5f);
    }
    __syncthreads();
    float mu = mu_s, rstd = rstd_s;
    float4 wv4 = reinterpret_cast<const float4*>(w)[threadIdx.x];
    float4 bv4 = reinterpret_cast<const float4*>(b)[threadIdx.x];
    ushort4 o;
    o.x = f2bf((v.x - mu) * rstd * wv4.x + bv4.x);
    o.y = f2bf((v.y - mu) * rstd * wv4.y + bv4.y);
    o.z = f2bf((v.z - mu) * rstd * wv4.z + bv4.z);
    o.w = f2bf((v.w - mu) * rstd * wv4.w + bv4.w);
    *reinterpret_cast<ushort4*>((ushort*)xn + (size_t)row * DMODEL + threadIdx.x * 4) = o;
}

// ---------------- f32 -> bf16 convert (weights) ------------------------------
__global__ __launch_bounds__(256) void cvt_kernel(const float* __restrict__ in,
                                                  __hip_bfloat16* __restrict__ o) {
    int i = (blockIdx.x * 256 + threadIdx.x) * 4;
    float4 v = *reinterpret_cast<const float4*>(in + i);
    ushort4 p;
    p.x = f2bf(v.x); p.y = f2bf(v.y); p.z = f2bf(v.z); p.w = f2bf(v.w);
    *reinterpret_cast<ushort4*>((ushort*)o + i) = p;
}

// ---------------- bf16 MFMA GEMM: C[M,N] = A[M,K] @ W[N,K]^T  ----------------
// 128x128 tile, BK=32, 4 waves (2x2), each wave 64x64 via 4x4 16x16x32 frags.
// EPI 0: split store (n < nsplit -> C, else C2, both ldc row stride, fp32)
// EPI 2: C[m*ldc+n] = acc + R[m*ldc+n]
template <int EPI>
__global__ __launch_bounds__(256) void gemm_bf16(
    const __hip_bfloat16* __restrict__ A, int lda,
    const __hip_bfloat16* __restrict__ W, int ldw,
    float* __restrict__ C, float* __restrict__ C2, int nsplit, int ldc,
    int K, const float* __restrict__ R) {
    __shared__ ushort As[128][32];
    __shared__ ushort Bs[128][32];
    int tid = threadIdx.x;
    int w = tid >> 6, lane = tid & 63;
    int m0 = blockIdx.y * 128, n0 = blockIdx.x * 128;
    int wr = w >> 1, wc = w & 1;

    int srow = (w << 4) + (lane >> 2);
    int skoff = (lane & 3) << 3;
    const ushort* gA = (const ushort*)A + (size_t)(m0 + srow) * lda + skoff;
    const ushort* gB = (const ushort*)W + (size_t)(n0 + srow) * ldw + skoff;
    char* ldsA0 = (char*)&As[0][0] + w * 1024;
    char* ldsB0 = (char*)&Bs[0][0] + w * 1024;

    f32x4 acc[4][4] = {};
    int frow = (lane & 15);
    int fk   = (lane >> 4) << 3;

    for (int k0 = 0; k0 < K; k0 += 32) {
        __syncthreads();
        __builtin_amdgcn_global_load_lds((as1_cvoid*)(gA + k0),                    (as3_void*)(ldsA0),        16, 0, 0);
        __builtin_amdgcn_global_load_lds((as1_cvoid*)(gA + (size_t)64 * lda + k0), (as3_void*)(ldsA0 + 4096), 16, 0, 0);
        __builtin_amdgcn_global_load_lds((as1_cvoid*)(gB + k0),                    (as3_void*)(ldsB0),        16, 0, 0);
        __builtin_amdgcn_global_load_lds((as1_cvoid*)(gB + (size_t)64 * ldw + k0), (as3_void*)(ldsB0 + 4096), 16, 0, 0);
        __syncthreads();

        bf16x8 af[4], bfr[4];
#pragma unroll
        for (int mi = 0; mi < 4; mi++)
            af[mi] = *(const bf16x8*)&As[wr * 64 + mi * 16 + frow][fk];
#pragma unroll
        for (int ni = 0; ni < 4; ni++)
            bfr[ni] = *(const bf16x8*)&Bs[wc * 64 + ni * 16 + frow][fk];
#pragma unroll
        for (int mi = 0; mi < 4; mi++)
#pragma unroll
            for (int ni = 0; ni < 4; ni++)
                acc[mi][ni] = __builtin_amdgcn_mfma_f32_16x16x32_bf16(
                    af[mi], bfr[ni], acc[mi][ni], 0, 0, 0);
    }

    int crow = (lane >> 4) << 2;
    int ccol = lane & 15;
    float* Cb = C;
    int nbase = n0;
    if (EPI == 0 && n0 >= nsplit) { Cb = C2; nbase = n0 - nsplit; }
#pragma unroll
    for (int mi = 0; mi < 4; mi++) {
#pragma unroll
        for (int ni = 0; ni < 4; ni++) {
#pragma unroll
            for (int r = 0; r < 4; r++) {
                int m = m0 + wr * 64 + mi * 16 + crow + r;
                int n = nbase + wc * 64 + ni * 16 + ccol;
                float v = acc[mi][ni][r];
                if (EPI == 2) v += R[(size_t)m * ldc + n];
                Cb[(size_t)m * ldc + n] = v;
            }
        }
    }
}

// ---------------- fp32 GEMM (dt_proj) ----------------------------------------
template <int EPI>
__global__ __launch_bounds__(256) void gemm_kernel(
    const float* __restrict__ A, int lda,
    const float* __restrict__ W, int ldw,
    float* __restrict__ C, int ldc,
    int N, int K,
    const float* __restrict__ bias) {
    __shared__ float As[16][64];
    __shared__ float Ws[16][64];
    int m0 = blockIdx.y * 64;
    int n0 = blockIdx.x * 64;
    int tid = threadIdx.x;
    int tm = tid >> 4, tn = tid & 15;
    int lr = tid >> 2;
    int lk = (tid & 3) << 2;

    float acc[4][4] = {};

    for (int k0 = 0; k0 < K; k0 += 16) {
        float4 av = *reinterpret_cast<const float4*>(A + (size_t)(m0 + lr) * lda + k0 + lk);
        float4 wvv;
        int wn = n0 + lr;
        if (wn < N)
            wvv = *reinterpret_cast<const float4*>(W + (size_t)wn * ldw + k0 + lk);
        else
            wvv = make_float4(0.f, 0.f, 0.f, 0.f);
        __syncthreads();
        As[lk + 0][lr] = av.x; As[lk + 1][lr] = av.y;
        As[lk + 2][lr] = av.z; As[lk + 3][lr] = av.w;
        Ws[lk + 0][lr] = wvv.x; Ws[lk + 1][lr] = wvv.y;
        Ws[lk + 2][lr] = wvv.z; Ws[lk + 3][lr] = wvv.w;
        __syncthreads();
#pragma unroll
        for (int k = 0; k < 16; k++) {
            float4 a = *reinterpret_cast<const float4*>(&As[k][tm << 2]);
            float4 bv = *reinterpret_cast<const float4*>(&Ws[k][tn << 2]);
            float ar[4] = {a.x, a.y, a.z, a.w};
            float br[4] = {bv.x, bv.y, bv.z, bv.w};
#pragma unroll
            for (int i = 0; i < 4; i++)
#pragma unroll
                for (int j = 0; j < 4; j++)
                    acc[i][j] = fmaf(ar[i], br[j], acc[i][j]);
        }
    }
#pragma unroll
    for (int i = 0; i < 4; i++) {
        int m = m0 + (tm << 2) + i;
#pragma unroll
        for (int j = 0; j < 4; j++) {
            int n = n0 + (tn << 2) + j;
            if (n < N) {
                float v = acc[i][j];
                if (EPI == 1) {
                    v += bias[n];
                    v = (v > 20.f) ? v : log1pf(__expf(v));
                }
                C[(size_t)m * ldc + n] = v;
            }
        }
    }
}

// ---------------- x_proj split-K: partial + reduce ---------------------------
// P[kz][m][n] = u[m, kz*128:(kz+1)*128] @ W[n, same]^T   (n < 96)
__global__ __launch_bounds__(256) void xp_partial(
    const float* __restrict__ A,   // u [4096][2048]
    const float* __restrict__ W,   // x_proj_w [96][2048]
    float* __restrict__ P) {       // [KS][4096][96]
    __shared__ float As[16][64];
    __shared__ float Ws[16][64];
    int m0 = blockIdx.y * 64;
    int n0 = blockIdx.x * 64;      // 0 or 64
    int kbase = blockIdx.z * KCH;
    int tid = threadIdx.x;
    int tm = tid >> 4, tn = tid & 15;
    int lr = tid >> 2;
    int lk = (tid & 3) << 2;

    float acc[4][4] = {};

    for (int k0 = kbase; k0 < kbase + KCH; k0 += 16) {
        float4 av = *reinterpret_cast<const float4*>(A + (size_t)(m0 + lr) * DINNER + k0 + lk);
        float4 wvv;
        int wn = n0 + lr;
        if (wn < 96)
            wvv = *reinterpret_cast<const float4*>(W + (size_t)wn * DINNER + k0 + lk);
        else
            wvv = make_float4(0.f, 0.f, 0.f, 0.f);
        __syncthreads();
        As[lk + 0][lr] = av.x; As[lk + 1][lr] = av.y;
        As[lk + 2][lr] = av.z; As[lk + 3][lr] = av.w;
        Ws[lk + 0][lr] = wvv.x; Ws[lk + 1][lr] = wvv.y;
        Ws[lk + 2][lr] = wvv.z; Ws[lk + 3][lr] = wvv.w;
        __syncthreads();
#pragma unroll
        for (int k = 0; k < 16; k++) {
            float4 a = *reinterpret_cast<const float4*>(&As[k][tm << 2]);
            float4 bv = *reinterpret_cast<const float4*>(&Ws[k][tn << 2]);
            float ar[4] = {a.x, a.y, a.z, a.w};
            float br[4] = {bv.x, bv.y, bv.z, bv.w};
#pragma unroll
            for (int i = 0; i < 4; i++)
#pragma unroll
                for (int j = 0; j < 4; j++)
                    acc[i][j] = fmaf(ar[i], br[j], acc[i][j]);
        }
    }
    float* Pz = P + (size_t)blockIdx.z * NROWS * 96;
#pragma unroll
    for (int i = 0; i < 4; i++) {
        int m = m0 + (tm << 2) + i;
#pragma unroll
        for (int j = 0; j < 4; j++) {
            int n = n0 + (tn << 2) + j;
            if (n < 96)
                Pz[(size_t)m * 96 + n] = acc[i][j];
        }
    }
}

__global__ __launch_bounds__(256) void xp_reduce(
    const float* __restrict__ P, float* __restrict__ xdbl) {
    int i = blockIdx.x * 256 + threadIdx.x;   // 4096*96 outputs
    float s = 0.f;
#pragma unroll
    for (int z = 0; z < KS; z++)
        s += P[(size_t)z * NROWS * 96 + i];
    xdbl[i] = s;
}

// ------------- causal depthwise conv (width 4) + SiLU ------------------------
__global__ __launch_bounds__(256) void conv_silu_kernel(
    const float* __restrict__ xc, const float* __restrict__ cw,
    const float* __restrict__ cb, float* __restrict__ u) {
    int c = blockIdx.x * 256 + threadIdx.x;
    int r = blockIdx.y;
    int l = r & (LL - 1);
    float4 wv = reinterpret_cast<const float4*>(cw)[c];
    const float* p = xc + (size_t)r * DINNER + c;
    float acc = cb[c];
    if (l >= 3) acc = fmaf(p[-3 * DINNER], wv.x, acc);
    if (l >= 2) acc = fmaf(p[-2 * DINNER], wv.y, acc);
    if (l >= 1) acc = fmaf(p[-1 * DINNER], wv.z, acc);
    acc = fmaf(p[0], wv.w, acc);
    float sig = 1.f / (1.f + __expf(-acc));
    u[(size_t)r * DINNER + c] = acc * sig;
}

// ------------------- chunked selective scan ---------------------------------
__global__ __launch_bounds__(256) void scan_pass1(
    const float* __restrict__ dt, const float* __restrict__ u,
    const float* __restrict__ xdbl, const float* __restrict__ A_log,
    float* __restrict__ hloc, float* __restrict__ aprod) {
    int bc = blockIdx.x >> 3;
    int b = bc >> 5, c = bc & (NC - 1);
    int d = ((blockIdx.x & 7) << 8) + threadIdx.x;
    float a2[DSTATE];
#pragma unroll
    for (int s = 0; s < DSTATE; s++)
        a2[s] = -__expf(A_log[d * DSTATE + s]) * 1.44269504089f;
    float h[DSTATE], ap[DSTATE];
#pragma unroll
    for (int s = 0; s < DSTATE; s++) { h[s] = 0.f; ap[s] = 1.f; }

    int t0 = c * CK;
    const float* dtp = dt + ((size_t)b * LL + t0) * DINNER + d;
    const float* up  = u  + ((size_t)b * LL + t0) * DINNER + d;
    const float* xr0 = xdbl + ((size_t)b * LL + t0) * 96;

    for (int t = 0; t < CK; t++) {
        float dtv = dtp[(size_t)t * DINNER];
        float uv  = up[(size_t)t * DINNER];
        float du  = dtv * uv;
        const float* xr = xr0 + t * 96;
#pragma unroll
        for (int s = 0; s < DSTATE; s++) {
            float dA = exp2f(dtv * a2[s]);
            h[s] = fmaf(dA, h[s], du * xr[64 + s]);
            ap[s] *= dA;
        }
    }
    size_t base = ((size_t)bc * DSTATE) * DINNER + d;
#pragma unroll
    for (int s = 0; s < DSTATE; s++) {
        hloc[base + (size_t)s * DINNER]  = h[s];
        aprod[base + (size_t)s * DINNER] = ap[s];
    }
}

__global__ __launch_bounds__(256) void scan_pass2(
    float* __restrict__ hloc, const float* __restrict__ aprod) {
    int idx = blockIdx.x * 256 + threadIdx.x;
    int d = idx & (DINNER - 1);
    int s = (idx >> 11) & (DSTATE - 1);
    int b = idx >> 15;
    float run = 0.f;
    for (int c = 0; c < NC; c++) {
        size_t off = ((size_t)((b * NC + c) * DSTATE + s)) * DINNER + d;
        float hl = hloc[off];
        float ap = aprod[off];
        hloc[off] = run;
        run = fmaf(ap, run, hl);
    }
}

__global__ __launch_bounds__(256) void scan_pass3(
    const float* __restrict__ dt, const float* __restrict__ u,
    const float* __restrict__ xdbl, const float* __restrict__ zb,
    const float* __restrict__ A_log, const float* __restrict__ Dp,
    const float* __restrict__ hinit, __hip_bfloat16* __restrict__ y) {
    int bc = blockIdx.x >> 3;
    int b = bc >> 5, c = bc & (NC - 1);
    int d = ((blockIdx.x & 7) << 8) + threadIdx.x;
    float a2[DSTATE];
#pragma unroll
    for (int s = 0; s < DSTATE; s++)
        a2[s] = -__expf(A_log[d * DSTATE + s]) * 1.44269504089f;
    float Dd = Dp[d];
    float h[DSTATE];
    size_t base = ((size_t)bc * DSTATE) * DINNER + d;
#pragma unroll
    for (int s = 0; s < DSTATE; s++) h[s] = hinit[base + (size_t)s * DINNER];

    int t0 = c * CK;
    const float* dtp = dt + ((size_t)b * LL + t0) * DINNER + d;
    const float* up  = u  + ((size_t)b * LL + t0) * DINNER + d;
    const float* zp  = zb + ((size_t)b * LL + t0) * DINNER + d;
    const float* xr0 = xdbl + ((size_t)b * LL + t0) * 96;
    ushort* yp = (ushort*)y + ((size_t)b * LL + t0) * DINNER + d;

    for (int t = 0; t < CK; t++) {
        float dtv = dtp[(size_t)t * DINNER];
        float uv  = up[(size_t)t * DINNER];
        float du  = dtv * uv;
        const float* xr = xr0 + t * 96;
        float yv = 0.f;
#pragma unroll
        for (int s = 0; s < DSTATE; s++) {
            float dA = exp2f(dtv * a2[s]);
            h[s] = fmaf(dA, h[s], du * xr[64 + s]);
            yv = fmaf(h[s], xr[80 + s], yv);
        }
        float zv = zp[(size_t)t * DINNER];
        float sig = 1.f / (1.f + __expf(-zv));
        yv = (yv + uv * Dd) * (zv * sig);
        yp[(size_t)t * DINNER] = f2bf(yv);
    }
}

// ---------------------------------------------------------------------------
extern "C" void kernel_launch(void* const* d_in, const int* in_sizes, int n_in,
                              void* d_out, int out_size, void* d_ws, size_t ws_size,
                              hipStream_t stream) {
    const float* x         = (const float*)d_in[0];
    const float* norm_w    = (const float*)d_in[1];
    const float* norm_b    = (const float*)d_in[2];
    const float* in_proj_w = (const float*)d_in[3];
    const float* conv_w    = (const float*)d_in[4];
    const float* conv_b    = (const float*)d_in[5];
    const float* x_proj_w  = (const float*)d_in[6];
    const float* dt_proj_w = (const float*)d_in[7];
    const float* dt_proj_b = (const float*)d_in[8];
    const float* A_log     = (const float*)d_in[9];
    const float* Dp        = (const float*)d_in[10];
    const float* out_proj_w= (const float*)d_in[11];
    float* out = (float*)d_out;

    float* ws   = (float*)d_ws;
    const size_t NI = (size_t)NROWS * DINNER;          // 8,388,608
    float* xc   = ws;                                  // [4096][2048] x-branch
    float* zb   = xc + NI;                             // [4096][2048] gate z
    float* u    = zb + NI;
    float* dtb  = u + NI;
    float* xdbl = dtb + NI;                            // [4096][96]
    __hip_bfloat16* xnb = (__hip_bfloat16*)(xdbl + (size_t)NROWS * 96);
    __hip_bfloat16* ybb = xnb + (size_t)NROWS * DMODEL;
    __hip_bfloat16* wib = ybb + NI;                    // in_proj_w bf16
    __hip_bfloat16* wob = wib + (size_t)2 * DINNER * DMODEL;  // out_proj_w bf16
    // scan scratch aliases xc (dead after conv)
    float* hloc  = xc;
    float* aprod = xc + (size_t)BB * NC * DSTATE * DINNER;
    // x_proj split-K partials alias dtb (dead until dt_proj): KS*4096*96 = 6.29M < 8.39M
    float* xpp   = dtb;

    // 1) LayerNorm -> bf16
    ln_kernel<<<NROWS, 256, 0, stream>>>(x, norm_w, norm_b, xnb);
    // 1b) weight converts
    cvt_kernel<<<(2 * DINNER * DMODEL) / 1024, 256, 0, stream>>>(in_proj_w, wib);
    cvt_kernel<<<(DMODEL * DINNER) / 1024, 256, 0, stream>>>(out_proj_w, wob);
    // 2) in_proj (bf16 MFMA): writes xc (n<2048) and zb (n>=2048)
    gemm_bf16<0><<<dim3((2 * DINNER) / 128, NROWS / 128), 256, 0, stream>>>(
        xnb, DMODEL, wib, DMODEL, xc, zb, DINNER, DINNER, DMODEL, nullptr);
    // 3) conv + SiLU -> u
    conv_silu_kernel<<<dim3(DINNER / 256, NROWS), 256, 0, stream>>>(xc, conv_w, conv_b, u);
    // 4) x_proj split-K: partials then reduce -> xdbl
    xp_partial<<<dim3(2, NROWS / 64, KS), 256, 0, stream>>>(u, x_proj_w, xpp);
    xp_reduce<<<(NROWS * 96) / 256, 256, 0, stream>>>(xpp, xdbl);
    // 5) dt_proj + softplus (fp32)  (overwrites dtb / xpp alias)
    gemm_kernel<1><<<dim3(DINNER / 64, NROWS / 64), 256, 0, stream>>>(
        xdbl, 96, dt_proj_w, DTRANK, dtb, DINNER, DINNER, DTRANK, dt_proj_b);
    // 6) chunked selective scan -> ybb (bf16)
    scan_pass1<<<BB * NC * (DINNER / 256), 256, 0, stream>>>(dtb, u, xdbl, A_log, hloc, aprod);
    scan_pass2<<<(BB * DSTATE * DINNER) / 256, 256, 0, stream>>>(hloc, aprod);
    scan_pass3<<<BB * NC * (DINNER / 256), 256, 0, stream>>>(dtb, u, xdbl, zb, A_log, Dp, hloc, ybb);
    // 7) out_proj + residual (bf16 MFMA)
    gemm_bf16<2><<<dim3(DMODEL / 128, NROWS / 128), 256, 0, stream>>>(
        ybb, DINNER, wob, DINNER, out, nullptr, 1 << 30, DMODEL, DINNER, x);
}